// Round 12
// baseline (69.392 us; speedup 1.0000x reference)
//
#include <hip/hip_runtime.h>

#define S_LEN 8192
#define DIM   64
#define WIN   64
#define QB    64            // queries per block
#define ROWS  192           // QB + 2*WIN staged K/V rows
#define KP    72            // K/Q LDS row pad (halves): 144B rows, conflict-free
#define VP    200           // V^T LDS row pad (halves): 400B rows, conflict-free
#define CP    68            // combine row pad (floats): 16B-aligned rows
#define NXCD  8

typedef _Float16 half8  __attribute__((ext_vector_type(8)));
typedef _Float16 half4t __attribute__((ext_vector_type(4)));
typedef float    f32x4  __attribute__((ext_vector_type(4)));

__global__ __launch_bounds__(512, 1)
void swa_fwd(const float* __restrict__ qg,
             const float* __restrict__ kg,
             const float* __restrict__ vg,
             float* __restrict__ outg) {
    // LDS: [K 192x72 | Q 64x72] fp16 (36864 B, later overlaid by comb) + VT 64x200 fp16
    __shared__ __align__(16) _Float16 lds_kq[(ROWS + QB) * KP];
    __shared__ __align__(16) _Float16 lds_vt[DIM * VP];
    __shared__ float comb_l[128];
    _Float16* Kl = lds_kq;                      // [192][72]
    _Float16* Ql = lds_kq + ROWS * KP;          // [64][72]
    float*    comb = reinterpret_cast<float*>(lds_kq);  // [128][CP] overlay, 34816 B

    const int nwg = gridDim.x, cpx = nwg / NXCD;
    const int lb  = (blockIdx.x % NXCD) * cpx + blockIdx.x / NXCD;
    const int nqb = S_LEN / QB;
    const int b   = lb / nqb, s0 = (lb % nqb) * QB;
    const int tid = threadIdx.x;
    const int c0  = s0 - WIN;
    const float qscale = 0.125f * 1.44269504088896340736f;

    // ---- issue ALL global loads first: K (6 f4), Q (2 f4), V (24 dwords)
    float4 kreg[6];
    #pragma unroll
    for (int i = 0; i < 6; ++i) {
        int f = tid + i * 512;              // < 3072
        int row = f >> 4, c4 = (f & 15) << 2;
        int gr = c0 + row; gr = gr < 0 ? 0 : (gr > S_LEN - 1 ? S_LEN - 1 : gr);
        kreg[i] = *reinterpret_cast<const float4*>(kg + (b * S_LEN + gr) * DIM + c4);
    }
    float4 qreg2[2];
    #pragma unroll
    for (int i = 0; i < 2; ++i) {
        int f = tid + i * 512;              // < 1024
        int row = f >> 4, c4 = (f & 15) << 2;
        qreg2[i] = *reinterpret_cast<const float4*>(qg + (b * S_LEN + s0 + row) * DIM + c4);
    }
    const int vn = tid & 63;                // V^T: this thread owns column n
    const int vk0 = (tid >> 6) * 24;        // and k-rows [vk0, vk0+24)
    float vreg[24];
    #pragma unroll
    for (int j = 0; j < 24; ++j) {
        int gr = c0 + vk0 + j; gr = gr < 0 ? 0 : (gr > S_LEN - 1 ? S_LEN - 1 : gr);
        vreg[j] = vg[(b * S_LEN + gr) * DIM + vn];
    }

    // ---- cvt + LDS-write K and Q (compiler waits only on K/Q loads: V flies on)
    #pragma unroll
    for (int i = 0; i < 6; ++i) {
        int f = tid + i * 512;
        int row = f >> 4, c4 = (f & 15) << 2;
        half4t h; h[0] = (_Float16)kreg[i].x; h[1] = (_Float16)kreg[i].y;
                  h[2] = (_Float16)kreg[i].z; h[3] = (_Float16)kreg[i].w;
        *reinterpret_cast<half4t*>(Kl + row * KP + c4) = h;
    }
    #pragma unroll
    for (int i = 0; i < 2; ++i) {
        int f = tid + i * 512;
        int row = f >> 4, c4 = (f & 15) << 2;
        half4t h; h[0] = (_Float16)(qreg2[i].x * qscale); h[1] = (_Float16)(qreg2[i].y * qscale);
                  h[2] = (_Float16)(qreg2[i].z * qscale); h[3] = (_Float16)(qreg2[i].w * qscale);
        *reinterpret_cast<half4t*>(Ql + row * KP + c4) = h;
    }

    // ---- raw barrier: K/Q LDS visible; V global loads REMAIN IN FLIGHT
    __builtin_amdgcn_sched_barrier(0);
    asm volatile("s_waitcnt lgkmcnt(0)" ::: "memory");
    __builtin_amdgcn_s_barrier();
    __builtin_amdgcn_sched_barrier(0);

    // ---- wave tiling: qt = query 16-tile, h = key 96-half
    const int wv = tid >> 6, lane = tid & 63;
    const int qt = wv & 3, h = wv >> 2;
    const int col = lane & 15, g = lane >> 4;

    // Q B-frags (B[k][n]: col=q=lane&15, k = 8g+e contiguous)
    const _Float16* qrow = Ql + (16 * qt + col) * KP + 8 * g;
    half8 qf0 = *reinterpret_cast<const half8*>(qrow);
    half8 qf1 = *reinterpret_cast<const half8*>(qrow + 32);

    // ---- swapped QK^T: S^T[96 k x 16 q] = K * Q^T, fp32 accum
    f32x4 acc[6];
    #pragma unroll
    for (int t = 0; t < 6; ++t) acc[t] = (f32x4){0.f, 0.f, 0.f, 0.f};
    #pragma unroll
    for (int t = 0; t < 6; ++t) {
        const _Float16* kr = Kl + (96 * h + 16 * t + col) * KP + 8 * g;
        half8 a0 = *reinterpret_cast<const half8*>(kr);
        half8 a1 = *reinterpret_cast<const half8*>(kr + 32);
        acc[t] = __builtin_amdgcn_mfma_f32_16x16x32_f16(a0, qf0, acc[t], 0, 0, 0);
        acc[t] = __builtin_amdgcn_mfma_f32_16x16x32_f16(a1, qf1, acc[t], 0, 0, 0);
    }

    // ---- mask + exp2 (scale folded into Q) + row-sum l
    const int qglob = s0 + 16 * qt + col;
    const int kb = c0 + 96 * h + 4 * g;     // + 16t + j = key global row
    float ev[6][4];
    float lsum = 0.f;
    #pragma unroll
    for (int t = 0; t < 6; ++t) {
        #pragma unroll
        for (int j = 0; j < 4; ++j) {
            int kglob = kb + 16 * t + j;
            bool valid = ((unsigned)(kglob - qglob + WIN) <= 2u * WIN) &&
                         ((unsigned)kglob < (unsigned)S_LEN);
            float e = valid ? __builtin_amdgcn_exp2f(acc[t][j]) : 0.f;
            ev[t][j] = e; lsum += e;
        }
    }
    lsum += __shfl_xor(lsum, 16);
    lsum += __shfl_xor(lsum, 32);           // full sum over this k-half per query

    // ---- P^T -> PV A-frags in-register (lane already owns q = lane&15)
    const int srcA = col + 16 * ((2 * g) & 3);
    const int srcB = col + 16 * ((2 * g + 1) & 3);
    const int tsel = g >> 1;
    half8 pa[3];
    #pragma unroll
    for (int c = 0; c < 3; ++c) {
        float vals[8];
        #pragma unroll
        for (int j = 0; j < 4; ++j) {
            float a0 = __shfl(ev[2 * c][j], srcA, 64);
            float a1 = __shfl(ev[2 * c + 1][j], srcA, 64);
            vals[j] = tsel ? a1 : a0;
            float b0 = __shfl(ev[2 * c][j], srcB, 64);
            float b1 = __shfl(ev[2 * c + 1][j], srcB, 64);
            vals[4 + j] = tsel ? b1 : b0;
        }
        #pragma unroll
        for (int e = 0; e < 8; ++e) pa[c][e] = (_Float16)vals[e];
    }

    // ---- V landed by now (hidden under QK^T+softmax): cvt + write V^T
    asm volatile("s_waitcnt vmcnt(0)" ::: "memory");
    __builtin_amdgcn_sched_barrier(0);
    #pragma unroll
    for (int j2 = 0; j2 < 6; ++j2) {
        half4t hv;
        #pragma unroll
        for (int e = 0; e < 4; ++e) hv[e] = (_Float16)vreg[j2 * 4 + e];
        *reinterpret_cast<half4t*>(lds_vt + vn * VP + vk0 + j2 * 4) = hv;
    }
    asm volatile("s_waitcnt lgkmcnt(0)" ::: "memory");
    __builtin_amdgcn_s_barrier();
    __builtin_amdgcn_sched_barrier(0);

    // ---- PV: O[16 q x 64 n] += P[16 x 96] V[96 x 64]; B-frag from VT
    f32x4 oacc[4];
    #pragma unroll
    for (int n4 = 0; n4 < 4; ++n4) oacc[n4] = (f32x4){0.f, 0.f, 0.f, 0.f};
    #pragma unroll
    for (int n4 = 0; n4 < 4; ++n4) {
        #pragma unroll
        for (int c = 0; c < 3; ++c) {
            half8 vf = *reinterpret_cast<const half8*>(
                lds_vt + (16 * n4 + col) * VP + 96 * h + 32 * c + 8 * g);
            oacc[n4] = __builtin_amdgcn_mfma_f32_16x16x32_f16(pa[c], vf, oacc[n4], 0, 0, 0);
        }
    }

    // ---- combine the two k-halves via LDS overlay on dead K/Q
    __syncthreads();                        // all waves past K/Q/VT compute reads
    #pragma unroll
    for (int n4 = 0; n4 < 4; ++n4)
        #pragma unroll
        for (int j = 0; j < 4; ++j)
            comb[(wv * 16 + 4 * g + j) * CP + 16 * n4 + col] = oacc[n4][j];
    if (lane < 16) comb_l[wv * 16 + lane] = lsum;
    __syncthreads();

    // ---- final: thread -> (query, 8-dim chunk); sum halves, divide, store
    {
        int q = tid >> 3, nb = (tid & 7) * 8;
        int qt2 = q >> 4, qr = q & 15;
        const float* r0 = comb + (qt2 * 16 + qr) * CP + nb;
        const float* r1 = comb + ((4 + qt2) * 16 + qr) * CP + nb;
        float linv = 1.0f / (comb_l[qt2 * 16 + qr] + comb_l[(4 + qt2) * 16 + qr]);
        float4 a0 = *reinterpret_cast<const float4*>(r0);
        float4 a1 = *reinterpret_cast<const float4*>(r0 + 4);
        float4 b0 = *reinterpret_cast<const float4*>(r1);
        float4 b1 = *reinterpret_cast<const float4*>(r1 + 4);
        float* op = outg + (b * S_LEN + s0 + q) * DIM + nb;
        *reinterpret_cast<float4*>(op) =
            make_float4((a0.x + b0.x) * linv, (a0.y + b0.y) * linv,
                        (a0.z + b0.z) * linv, (a0.w + b0.w) * linv);
        *reinterpret_cast<float4*>(op + 4) =
            make_float4((a1.x + b1.x) * linv, (a1.y + b1.y) * linv,
                        (a1.z + b1.z) * linv, (a1.w + b1.w) * linv);
    }
}

extern "C" void kernel_launch(void* const* d_in, const int* in_sizes, int n_in,
                              void* d_out, int out_size, void* d_ws, size_t ws_size,
                              hipStream_t stream) {
    const float* q = (const float*)d_in[0];
    const float* k = (const float*)d_in[1];
    const float* v = (const float*)d_in[2];
    float* out = (float*)d_out;
    int B = in_sizes[0] / (S_LEN * DIM);
    dim3 grid(B * (S_LEN / QB));            // 256 blocks for B=2
    swa_fwd<<<grid, 512, 0, stream>>>(q, k, v, out);
}

// Round 14
// 68.198 us; speedup vs baseline: 1.0175x; 1.0175x over previous
//
#include <hip/hip_runtime.h>

#define S_LEN 8192
#define DIM   64
#define WIN   64
#define QB    64            // queries per block
#define ROWS  192           // QB + 2*WIN staged K/V rows
#define KP    72            // K/Q LDS row pad (halves): 144B rows, conflict-free
#define VP    200           // V^T LDS row pad (halves): 400B rows, conflict-free
#define CP    68            // combine row pad (floats): 16B-aligned rows
#define NXCD  8

typedef _Float16 half8  __attribute__((ext_vector_type(8)));
typedef _Float16 half4t __attribute__((ext_vector_type(4)));
typedef float    f32x4  __attribute__((ext_vector_type(4)));

__global__ __launch_bounds__(512, 2)
void swa_fwd(const float* __restrict__ qg,
             const float* __restrict__ kg,
             const float* __restrict__ vg,
             float* __restrict__ outg) {
    // LDS: [K 192x72 | Q 64x72] fp16 (36864 B, later overlaid by comb) + VT 64x200 fp16
    __shared__ __align__(16) _Float16 lds_kq[(ROWS + QB) * KP];
    __shared__ __align__(16) _Float16 lds_vt[DIM * VP];
    __shared__ float comb_l[128];
    _Float16* Kl = lds_kq;                      // [192][72]
    _Float16* Ql = lds_kq + ROWS * KP;          // [64][72]
    float*    comb = reinterpret_cast<float*>(lds_kq);  // [128][CP] overlay, 34816 B

    const int nwg = gridDim.x, cpx = nwg / NXCD;
    const int lb  = (blockIdx.x % NXCD) * cpx + blockIdx.x / NXCD;
    const int nqb = S_LEN / QB;
    const int b   = lb / nqb, s0 = (lb % nqb) * QB;
    const int tid = threadIdx.x;
    const int c0  = s0 - WIN;
    const float qscale = 0.125f * 1.44269504088896340736f;

    // ---- stage K fp32->fp16 row-major [192][72]; coalesced f4 loads
    #pragma unroll
    for (int i = 0; i < 6; ++i) {
        int f = tid + i * 512;              // < 3072
        int row = f >> 4, c4 = (f & 15) << 2;
        int gr = c0 + row; gr = gr < 0 ? 0 : (gr > S_LEN - 1 ? S_LEN - 1 : gr);
        float4 v = *reinterpret_cast<const float4*>(kg + (b * S_LEN + gr) * DIM + c4);
        half4t h; h[0] = (_Float16)v.x; h[1] = (_Float16)v.y;
                  h[2] = (_Float16)v.z; h[3] = (_Float16)v.w;
        *reinterpret_cast<half4t*>(Kl + row * KP + c4) = h;
    }
    // ---- stage Q (pre-scaled) [64][72]
    #pragma unroll
    for (int i = 0; i < 2; ++i) {
        int f = tid + i * 512;              // < 1024
        int row = f >> 4, c4 = (f & 15) << 2;
        float4 v = *reinterpret_cast<const float4*>(qg + (b * S_LEN + s0 + row) * DIM + c4);
        half4t h; h[0] = (_Float16)(v.x * qscale); h[1] = (_Float16)(v.y * qscale);
                  h[2] = (_Float16)(v.z * qscale); h[3] = (_Float16)(v.w * qscale);
        *reinterpret_cast<half4t*>(Ql + row * KP + c4) = h;
    }
    // ---- stage V TRANSPOSED [64 n][200 k]; dword loads coalesced per k-row
    {
        int n  = tid & 63;
        int k0 = (tid >> 6) * 24;
        #pragma unroll
        for (int j2 = 0; j2 < 6; ++j2) {
            int kq = k0 + j2 * 4;
            half4t h;
            #pragma unroll
            for (int e = 0; e < 4; ++e) {
                int gr = c0 + kq + e; gr = gr < 0 ? 0 : (gr > S_LEN - 1 ? S_LEN - 1 : gr);
                h[e] = (_Float16)vg[(b * S_LEN + gr) * DIM + n];
            }
            *reinterpret_cast<half4t*>(lds_vt + n * VP + kq) = h;
        }
    }
    __syncthreads();

    // ---- wave tiling: qt = query 16-tile, h = key 96-half
    const int wv = tid >> 6, lane = tid & 63;
    const int qt = wv & 3, h = wv >> 2;
    const int col = lane & 15, g = lane >> 4;

    // Q B-frags (B[k][n]: col=q=lane&15, k = 8g+e contiguous)
    const _Float16* qrow = Ql + (16 * qt + col) * KP + 8 * g;
    half8 qf0 = *reinterpret_cast<const half8*>(qrow);
    half8 qf1 = *reinterpret_cast<const half8*>(qrow + 32);

    // ---- swapped QK^T: S^T[96 k x 16 q] = K * Q^T, fp32 accum
    f32x4 acc[6];
    #pragma unroll
    for (int t = 0; t < 6; ++t) acc[t] = (f32x4){0.f, 0.f, 0.f, 0.f};
    #pragma unroll
    for (int t = 0; t < 6; ++t) {
        const _Float16* kr = Kl + (96 * h + 16 * t + col) * KP + 8 * g;
        half8 a0 = *reinterpret_cast<const half8*>(kr);
        half8 a1 = *reinterpret_cast<const half8*>(kr + 32);
        acc[t] = __builtin_amdgcn_mfma_f32_16x16x32_f16(a0, qf0, acc[t], 0, 0, 0);
        acc[t] = __builtin_amdgcn_mfma_f32_16x16x32_f16(a1, qf1, acc[t], 0, 0, 0);
    }

    // ---- mask + exp2 (scale already folded into Q) + row-sum l
    const int qglob = s0 + 16 * qt + col;
    const int kb = c0 + 96 * h + 4 * g;     // + 16t + j = key global row
    float ev[6][4];
    float lsum = 0.f;
    #pragma unroll
    for (int t = 0; t < 6; ++t) {
        #pragma unroll
        for (int j = 0; j < 4; ++j) {
            int kglob = kb + 16 * t + j;
            bool valid = ((unsigned)(kglob - qglob + WIN) <= 2u * WIN) &&
                         ((unsigned)kglob < (unsigned)S_LEN);
            float e = valid ? __builtin_amdgcn_exp2f(acc[t][j]) : 0.f;
            ev[t][j] = e; lsum += e;
        }
    }
    lsum += __shfl_xor(lsum, 16);
    lsum += __shfl_xor(lsum, 32);           // full sum over this k-half per query

    // ---- P^T -> PV A-frags in-register (lane already owns q = lane&15)
    // A-frag elem e needs P row r = 32c + 8g + e, held by lane group
    // g' = (2g + (e>>2)) & 3 in tile t = 2c + (g>>1), reg j = e&3.
    const int srcA = col + 16 * ((2 * g) & 3);
    const int srcB = col + 16 * ((2 * g + 1) & 3);
    const int tsel = g >> 1;
    half8 pa[3];
    #pragma unroll
    for (int c = 0; c < 3; ++c) {
        float vals[8];
        #pragma unroll
        for (int j = 0; j < 4; ++j) {
            float a0 = __shfl(ev[2 * c][j], srcA, 64);
            float a1 = __shfl(ev[2 * c + 1][j], srcA, 64);
            vals[j] = tsel ? a1 : a0;
            float b0 = __shfl(ev[2 * c][j], srcB, 64);
            float b1 = __shfl(ev[2 * c + 1][j], srcB, 64);
            vals[4 + j] = tsel ? b1 : b0;
        }
        #pragma unroll
        for (int e = 0; e < 8; ++e) pa[c][e] = (_Float16)vals[e];
    }

    // ---- PV: O[16 q x 64 n] += P[16 x 96] V[96 x 64]; B-frag from VT
    f32x4 oacc[4];
    #pragma unroll
    for (int n4 = 0; n4 < 4; ++n4) oacc[n4] = (f32x4){0.f, 0.f, 0.f, 0.f};
    #pragma unroll
    for (int n4 = 0; n4 < 4; ++n4) {
        #pragma unroll
        for (int c = 0; c < 3; ++c) {
            half8 vf = *reinterpret_cast<const half8*>(
                lds_vt + (16 * n4 + col) * VP + 96 * h + 32 * c + 8 * g);
            oacc[n4] = __builtin_amdgcn_mfma_f32_16x16x32_f16(pa[c], vf, oacc[n4], 0, 0, 0);
        }
    }

    // ---- combine the two k-halves via LDS overlay on dead K/Q
    __syncthreads();                        // all waves past K/Q reads
    #pragma unroll
    for (int n4 = 0; n4 < 4; ++n4)
        #pragma unroll
        for (int j = 0; j < 4; ++j)
            comb[(wv * 16 + 4 * g + j) * CP + 16 * n4 + col] = oacc[n4][j];
    if (lane < 16) comb_l[wv * 16 + lane] = lsum;
    __syncthreads();

    // ---- final: thread -> (query, 8-dim chunk); sum halves, divide, store
    {
        int q = tid >> 3, nb = (tid & 7) * 8;
        int qt2 = q >> 4, qr = q & 15;
        const float* r0 = comb + (qt2 * 16 + qr) * CP + nb;
        const float* r1 = comb + ((4 + qt2) * 16 + qr) * CP + nb;
        float linv = 1.0f / (comb_l[qt2 * 16 + qr] + comb_l[(4 + qt2) * 16 + qr]);
        float4 a0 = *reinterpret_cast<const float4*>(r0);
        float4 a1 = *reinterpret_cast<const float4*>(r0 + 4);
        float4 b0 = *reinterpret_cast<const float4*>(r1);
        float4 b1 = *reinterpret_cast<const float4*>(r1 + 4);
        float* op = outg + (b * S_LEN + s0 + q) * DIM + nb;
        *reinterpret_cast<float4*>(op) =
            make_float4((a0.x + b0.x) * linv, (a0.y + b0.y) * linv,
                        (a0.z + b0.z) * linv, (a0.w + b0.w) * linv);
        *reinterpret_cast<float4*>(op + 4) =
            make_float4((a1.x + b1.x) * linv, (a1.y + b1.y) * linv,
                        (a1.z + b1.z) * linv, (a1.w + b1.w) * linv);
    }
}

extern "C" void kernel_launch(void* const* d_in, const int* in_sizes, int n_in,
                              void* d_out, int out_size, void* d_ws, size_t ws_size,
                              hipStream_t stream) {
    const float* q = (const float*)d_in[0];
    const float* k = (const float*)d_in[1];
    const float* v = (const float*)d_in[2];
    float* out = (float*)d_out;
    int B = in_sizes[0] / (S_LEN * DIM);
    dim3 grid(B * (S_LEN / QB));            // 256 blocks for B=2
    swa_fwd<<<grid, 512, 0, stream>>>(q, k, v, out);
}